// Round 6
// baseline (134.390 us; speedup 1.0000x reference)
//
#include <hip/hip_runtime.h>
#include <hip/hip_bf16.h>
#include <stdint.h>

#define B_ 32
#define L_ 4096
#define C_ 256
#define O_ 256
#define K_ 3
#define KN_ 4
#define A_ 16
#define LP_ 4098   // padded rows per batch: p = l+1; p=0 and p=4097 are zero pads

typedef unsigned short u16;
typedef __attribute__((ext_vector_type(8))) short bf16x8;
typedef __attribute__((ext_vector_type(4))) float f32x4;

static __device__ __forceinline__ u16 f2bf(float f) {
    union { float f; uint32_t u; } v; v.f = f;
    uint32_t u = v.u;
    u += 0x7fffu + ((u >> 16) & 1u);   // round-to-nearest-even
    return (u16)(u >> 16);
}

// ---------------- kernel 1: fused pool partials + x -> LINEAR bf16 (padded rows) ----------------
__global__ __launch_bounds__(256) void poolcvt_k(const float* __restrict__ x,
                                                 u16* __restrict__ xb,
                                                 float* __restrict__ part) {
    __shared__ float red[4][256];
    int bid = blockIdx.x;
    int b = bid >> 5, chunk = bid & 31;
    int t = threadIdx.x;
    int w = t >> 6, lane = t & 63;
    int c0 = lane << 2;
    f32x4 s = {0.f, 0.f, 0.f, 0.f};
    const float* xp = x + ((size_t)b * L_ + (size_t)chunk * 128) * C_ + c0;
    u16* xbb = xb + ((size_t)b * LP_ + (size_t)chunk * 128 + 1) * 256;
    #pragma unroll 4
    for (int it = 0; it < 32; ++it) {
        int rl = it * 4 + w;
        float4 v = *reinterpret_cast<const float4*>(xp + (size_t)rl * C_);
        s.x += v.x; s.y += v.y; s.z += v.z; s.w += v.w;
        ushort4 hv;
        hv.x = f2bf(v.x); hv.y = f2bf(v.y); hv.z = f2bf(v.z); hv.w = f2bf(v.w);
        *reinterpret_cast<ushort4*>(xbb + (size_t)rl * 256 + c0) = hv;
    }
    *reinterpret_cast<f32x4*>(&red[w][c0]) = s;
    __syncthreads();
    part[((size_t)bid << 8) + t] = red[0][t] + red[1][t] + red[2][t] + red[3][t];
    if (chunk == 0 && t < 64)
        *reinterpret_cast<ushort4*>(xb + (size_t)b * LP_ * 256 + t * 4) = make_ushort4(0, 0, 0, 0);
    if (chunk == 31 && t < 64)
        *reinterpret_cast<ushort4*>(xb + ((size_t)b * LP_ + LP_ - 1) * 256 + t * 4) = make_ushort4(0, 0, 0, 0);
}

// ---------------- kernel 1 (fallback): pooling partials only ----------------
__global__ __launch_bounds__(256) void pool_partial_k(const float* __restrict__ x,
                                                      float* __restrict__ part) {
    int bid = blockIdx.x;
    int b = bid >> 5, ch = bid & 31;
    int c = threadIdx.x;
    const float* p = x + (size_t)(b * L_ + ch * 128) * C_ + c;
    float s = 0.f;
    #pragma unroll 4
    for (int l = 0; l < 128; ++l) s += p[(size_t)l * C_];
    part[((size_t)bid << 8) + c] = s;
}

// ---------------- kernel 2: attention head (per-batch) ----------------
__global__ __launch_bounds__(256) void att_k(const float* __restrict__ part,
    const float* __restrict__ w_fc, const float* __restrict__ bn_g,
    const float* __restrict__ bn_b, const float* __restrict__ bn_m,
    const float* __restrict__ bn_v,
    const float* __restrict__ w_ch, const float* __restrict__ b_ch,
    const float* __restrict__ w_fil, const float* __restrict__ b_fil,
    const float* __restrict__ w_sp, const float* __restrict__ b_sp,
    const float* __restrict__ w_ker, const float* __restrict__ b_ker,
    float* __restrict__ ch_att, float* __restrict__ fil_att,
    float* __restrict__ sp_att, float* __restrict__ ker_att) {
    __shared__ float pooled[C_];
    __shared__ float h[A_];
    int b = blockIdx.x, t = threadIdx.x;
    float s = 0.f;
    for (int j = 0; j < 32; ++j) s += part[(((size_t)(b * 32 + j)) << 8) + t];
    pooled[t] = s * (1.0f / L_);
    __syncthreads();
    if (t < A_) {
        float acc = 0.f;
        for (int c = 0; c < C_; ++c) acc += pooled[c] * w_fc[t * C_ + c];
        float sc = bn_g[t] * rsqrtf(bn_v[t] + 1e-5f);
        acc = (acc - bn_m[t]) * sc + bn_b[t];
        h[t] = fmaxf(acc, 0.f);
    }
    __syncthreads();
    {
        float a1 = b_ch[t], a2 = b_fil[t];
        for (int a = 0; a < A_; ++a) { a1 += h[a] * w_ch[t * A_ + a]; a2 += h[a] * w_fil[t * A_ + a]; }
        ch_att[b * C_ + t]  = 1.f / (1.f + expf(-a1));
        fil_att[b * O_ + t] = 1.f / (1.f + expf(-a2));
    }
    if (t < K_) {
        float acc = b_sp[t];
        for (int a = 0; a < A_; ++a) acc += h[a] * w_sp[t * A_ + a];
        sp_att[b * 4 + t] = 1.f / (1.f + expf(-acc));
    }
    if (t == 0) {
        float lg[KN_], m = -1e30f;
        for (int n = 0; n < KN_; ++n) {
            float acc = b_ker[n];
            for (int a = 0; a < A_; ++a) acc += h[a] * w_ker[n * A_ + a];
            lg[n] = acc; m = fmaxf(m, acc);
        }
        float ss = 0.f;
        for (int n = 0; n < KN_; ++n) { lg[n] = expf(lg[n] - m); ss += lg[n]; }
        for (int n = 0; n < KN_; ++n) ker_att[b * 4 + n] = lg[n] / ss;
    }
}

// ---------------- kernel 3: effective weights -> bf16 MFMA-fragment layout ----------------
__global__ __launch_bounds__(256) void wfrag_k(const float* __restrict__ weight,
    const float* __restrict__ ch_att, const float* __restrict__ fil_att,
    const float* __restrict__ sp_att, const float* __restrict__ ker_att,
    u16* __restrict__ wf) {
    __shared__ float wlds[64 * 97];
    int beta = blockIdx.x;
    int ob = beta & 15, ic = (beta >> 4) & 7, bg = beta >> 7;
    int t = threadIdx.x;
    const size_t blk_base = (size_t)(ob * 16) * 768 + ic * 96;
    #pragma unroll
    for (int j = 0; j < 24; ++j) {
        int ei = t + (j << 8);
        int r = ei / 96, c = ei - r * 96;
        int n = r >> 4, ol = r & 15;
        wlds[r * 97 + c] = weight[((size_t)n * 256 + ol) * 768 + blk_base + c];
    }
    __syncthreads();
    int lane = t & 63, q = t >> 6;
    int o_l = lane & 15, ig = lane >> 4;
    int i0 = ig << 3;
    int o = (ob << 4) + o_l;
    int ig0 = (ic << 5) + i0;
    float wl[4][3][8];
    #pragma unroll
    for (int n = 0; n < 4; ++n) {
        int rb = (n * 16 + o_l) * 97;
        #pragma unroll
        for (int e = 0; e < 8; ++e) {
            int cb = rb + (i0 + e) * 3;
            wl[n][0][e] = wlds[cb];
            wl[n][1][e] = wlds[cb + 1];
            wl[n][2][e] = wlds[cb + 2];
        }
    }
    #pragma unroll
    for (int bi = 0; bi < 2; ++bi) {
        int b = (bg << 3) + (q << 1) + bi;
        float ka0 = ker_att[b * 4 + 0], ka1 = ker_att[b * 4 + 1];
        float ka2 = ker_att[b * 4 + 2], ka3 = ker_att[b * 4 + 3];
        float fil = fil_att[b * O_ + o];
        float ch8[8];
        *reinterpret_cast<float4*>(ch8)     = *reinterpret_cast<const float4*>(ch_att + b * C_ + ig0);
        *reinterpret_cast<float4*>(ch8 + 4) = *reinterpret_cast<const float4*>(ch_att + b * C_ + ig0 + 4);
        #pragma unroll
        for (int tap = 0; tap < 3; ++tap) {
            float fs = fil * sp_att[b * 4 + tap];
            union { u16 h[8]; uint4 v; } pk;
            #pragma unroll
            for (int e = 0; e < 8; ++e) {
                float acc = ka0 * wl[0][tap][e] + ka1 * wl[1][tap][e]
                          + ka2 * wl[2][tap][e] + ka3 * wl[3][tap][e];
                pk.h[e] = f2bf(acc * fs * ch8[e]);
            }
            size_t idx = ((((size_t)(b * 24 + tap * 8 + ic) * 16 + ob) * 64) + lane) << 3;
            *reinterpret_cast<uint4*>(wf + idx) = pk.v;
        }
    }
}

// ---------------- kernel 4: conv, 4-wave blocks + register-double-buffered K-loop ----------------
// grid 2048 (XCD swizzle); block 256 = 4 waves (wr = o-quadrant), l-tile 64.
// LDS: 66 rows x 512 B (33792 B), granule g16 of row r at slot (g16 ^ (r&7)).
__global__ __launch_bounds__(256, 2) void conv_k(const u16* __restrict__ xb,
    const u16* __restrict__ wf, float* __restrict__ out) {
    __shared__ uint4 lds4[2112];               // 33792 B
    char* lp = (char*)lds4;
    int phys = blockIdx.x;
    int logical = ((phys & 7) << 8) + (phys >> 3);   // 2048 = 8 XCD chunks x 256
    int b = logical >> 6, lb = logical & 63;
    int l0 = lb << 6;
    int tid = threadIdx.x;
    const u16* xbb = xb + (size_t)b * LP_ * 256;

    // ---- stage rows p = l0 .. l0+65 (bf16, swizzled ds_write) ----
    #pragma unroll
    for (int it = 0; it < 9; ++it) {
        int id = tid + (it << 8);
        if (id < 2112) {                        // 66 rows * 32 granules
            int r = id >> 5, g16 = id & 31;
            bf16x8 v = *reinterpret_cast<const bf16x8*>(xbb + ((size_t)(l0 + r) << 8) + g16 * 8);
            *reinterpret_cast<bf16x8*>(lp + r * 512 + ((g16 ^ (r & 7)) << 4)) = v;
        }
    }
    __syncthreads();

    int w = tid >> 6, lane = tid & 63;
    int wr = w;                                 // o-quadrant
    int lrow = lane & 15;
    int g = lane >> 4;

    f32x4 acc[4][4] = {};
    const u16* wp0 = wf + ((((size_t)(b * 24) * 16 + wr * 4) * 64 + lane) << 3);

    #define LOAD_AB(AF, BF, kc) do {                                              \
        const int tap_ = (kc) >> 3, ic_ = (kc) & 7;                               \
        _Pragma("unroll")                                                         \
        for (int m = 0; m < 4; ++m)                                               \
            AF[m] = *reinterpret_cast<const bf16x8*>(wp0 + (size_t)(kc) * 8192 + (m << 9)); \
        const int sb_ = (ic_ << 2) + g;                                           \
        _Pragma("unroll")                                                         \
        for (int n = 0; n < 4; ++n) {                                             \
            int row_ = n * 16 + lrow + tap_;                                      \
            BF[n] = *reinterpret_cast<const bf16x8*>(lp + row_ * 512 + ((sb_ ^ (row_ & 7)) << 4)); \
        }                                                                         \
    } while (0)

    #define DO_MFMA(AF, BF) do {                                                  \
        _Pragma("unroll")                                                         \
        for (int m = 0; m < 4; ++m)                                               \
            _Pragma("unroll")                                                     \
            for (int n = 0; n < 4; ++n)                                           \
                acc[m][n] = __builtin_amdgcn_mfma_f32_16x16x32_bf16(AF[m], BF[n], acc[m][n], 0, 0, 0); \
    } while (0)

    bf16x8 afA[4], bfA[4], afB[4], bfB[4];
    LOAD_AB(afA, bfA, 0);
    LOAD_AB(afB, bfB, 1);
    #pragma unroll
    for (int kc2 = 0; kc2 < 12; ++kc2) {
        DO_MFMA(afA, bfA);
        if (kc2 < 11) LOAD_AB(afA, bfA, 2 * kc2 + 2);
        DO_MFMA(afB, bfB);
        if (kc2 < 11) LOAD_AB(afB, bfB, 2 * kc2 + 3);
    }
    #undef LOAD_AB
    #undef DO_MFMA

    __syncthreads();   // waves done reading x tile; LDS reused below

    // ---- epilogue: per-wave LDS transpose -> 256B-run stores ----
    float* ep = (float*)(lp + w * 8192);
    size_t obase = (size_t)b * O_ * L_;
    #pragma unroll
    for (int c2 = 0; c2 < 2; ++c2) {
        #pragma unroll
        for (int m2 = 0; m2 < 2; ++m2) {
            int m = c2 * 2 + m2;
            #pragma unroll
            for (int n = 0; n < 4; ++n) {
                int l_loc = n * 16 + lrow;
                int sl = (l_loc >> 2);
                #pragma unroll
                for (int j = 0; j < 4; ++j) {
                    int o_loc = m2 * 16 + g * 4 + j;
                    ep[o_loc * 64 + ((sl ^ o_loc) & 15) * 4 + (l_loc & 3)] = acc[m][n][j];
                }
            }
        }
        #pragma unroll
        for (int og = 0; og < 8; ++og) {
            int o_loc = og * 4 + g;
            int l4 = lrow;
            float4 v = *reinterpret_cast<float4*>(ep + o_loc * 64 + ((l4 ^ o_loc) & 15) * 4);
            int o = wr * 64 + c2 * 32 + o_loc;
            *reinterpret_cast<float4*>(out + obase + (size_t)o * L_ + l0 + l4 * 4) = v;
        }
        if (c2 == 0) __syncthreads();
    }
}

// ---------------- kernel 4 (fallback): R2's reg-staged conv from f32 x ----------------
__global__ __launch_bounds__(512, 4) void conv_fb_k(const float* __restrict__ x,
    const u16* __restrict__ wf, float* __restrict__ out) {
    __shared__ uint4 lds4[4160];
    char* lp = (char*)lds4;
    int phys = blockIdx.x;
    int logical = ((phys & 7) << 7) + (phys >> 3);
    int b = logical >> 5, lb = logical & 31;
    int l0 = lb << 7;
    int tid = threadIdx.x;
    const size_t xbase = (size_t)b * L_ * C_;
    #pragma unroll 4
    for (int it = 0; it < 17; ++it) {
        int id = tid + (it << 9);
        if (id < 8320) {
            int r  = id >> 6;
            int i  = (id & 63) << 2;
            int lg = l0 - 1 + r;
            float4 v = make_float4(0.f, 0.f, 0.f, 0.f);
            if (lg >= 0 && lg < L_)
                v = *reinterpret_cast<const float4*>(x + xbase + (size_t)lg * C_ + i);
            ushort4 hv;
            hv.x = f2bf(v.x); hv.y = f2bf(v.y); hv.z = f2bf(v.z); hv.w = f2bf(v.w);
            int slot = (i >> 3) ^ (r & 7);
            int off = r * 512 + slot * 16 + ((i >> 2) & 1) * 8;
            *reinterpret_cast<ushort4*>(lp + off) = hv;
        }
    }
    __syncthreads();
    int w = tid >> 6, lane = tid & 63;
    int wr = w & 3, wc = w >> 2;
    int lrow = lane & 15;
    int g = lane >> 4;
    f32x4 acc[4][4] = {};
    for (int kc = 0; kc < 24; ++kc) {
        int t  = kc >> 3;
        int ic = kc & 7;
        bf16x8 af[4], bfr[4];
        const u16* wp = wf + ((((size_t)(b * 24 + kc) * 16 + wr * 4) * 64 + lane) << 3);
        #pragma unroll
        for (int m = 0; m < 4; ++m)
            af[m] = *reinterpret_cast<const bf16x8*>(wp + (m << 9));
        int slotbase = (ic << 2) + g;
        #pragma unroll
        for (int n = 0; n < 4; ++n) {
            int row = wc * 64 + n * 16 + lrow + t;
            int off = row * 512 + ((slotbase ^ (row & 7)) << 4);
            bfr[n] = *reinterpret_cast<const bf16x8*>(lp + off);
        }
        #pragma unroll
        for (int m = 0; m < 4; ++m)
            #pragma unroll
            for (int n = 0; n < 4; ++n)
                acc[m][n] = __builtin_amdgcn_mfma_f32_16x16x32_bf16(af[m], bfr[n], acc[m][n], 0, 0, 0);
    }
    __syncthreads();
    float* ep = (float*)(lp + w * 8192);
    size_t obase = (size_t)b * O_ * L_;
    int lcol = l0 + wc * 64;
    #pragma unroll
    for (int c2 = 0; c2 < 2; ++c2) {
        #pragma unroll
        for (int m2 = 0; m2 < 2; ++m2) {
            int m = c2 * 2 + m2;
            #pragma unroll
            for (int n = 0; n < 4; ++n) {
                int l_loc = n * 16 + lrow;
                int sl = (l_loc >> 2);
                #pragma unroll
                for (int j = 0; j < 4; ++j) {
                    int o_loc = m2 * 16 + g * 4 + j;
                    ep[o_loc * 64 + ((sl ^ o_loc) & 15) * 4 + (l_loc & 3)] = acc[m][n][j];
                }
            }
        }
        #pragma unroll
        for (int og = 0; og < 8; ++og) {
            int o_loc = og * 4 + g;
            int l4 = lrow;
            float4 v = *reinterpret_cast<float4*>(ep + o_loc * 64 + ((l4 ^ o_loc) & 15) * 4);
            int o = wr * 64 + c2 * 32 + o_loc;
            *reinterpret_cast<float4*>(out + obase + (size_t)o * L_ + lcol + l4 * 4) = v;
        }
        if (c2 == 0) __syncthreads();
    }
}

extern "C" void kernel_launch(void* const* d_in, const int* in_sizes, int n_in,
                              void* d_out, int out_size, void* d_ws, size_t ws_size,
                              hipStream_t stream) {
    const float* x      = (const float*)d_in[0];
    const float* weight = (const float*)d_in[1];
    const float* w_fc   = (const float*)d_in[2];
    const float* bn_g   = (const float*)d_in[3];
    const float* bn_b   = (const float*)d_in[4];
    const float* bn_m   = (const float*)d_in[5];
    const float* bn_v   = (const float*)d_in[6];
    const float* w_ch   = (const float*)d_in[7];
    const float* b_ch   = (const float*)d_in[8];
    const float* w_fil  = (const float*)d_in[9];
    const float* b_fil  = (const float*)d_in[10];
    const float* w_sp   = (const float*)d_in[11];
    const float* b_sp   = (const float*)d_in[12];
    const float* w_ker  = (const float*)d_in[13];
    const float* b_ker  = (const float*)d_in[14];
    float* out = (float*)d_out;
    char*  ws  = (char*)d_ws;

    float* part    = (float*)ws;                         // 1 MB
    float* ch_att  = (float*)(ws + (1 << 20));
    float* fil_att = ch_att + 32 * 256;
    float* sp_att  = fil_att + 32 * 256;
    float* ker_att = sp_att + 32 * 4;
    u16*   wfrag   = (u16*)(ws + (1 << 20) + 70 * 1024); // 12.6 MB
    u16*   xbf     = (u16*)(ws + (16u << 20));           // 32*4098*512 B = 67.1 MB
    const size_t need = (16u << 20) + (size_t)B_ * LP_ * 512;

    if (ws_size >= need) {
        poolcvt_k<<<1024, 256, 0, stream>>>(x, xbf, part);
        att_k<<<32, 256, 0, stream>>>(part, w_fc, bn_g, bn_b, bn_m, bn_v,
                                      w_ch, b_ch, w_fil, b_fil, w_sp, b_sp, w_ker, b_ker,
                                      ch_att, fil_att, sp_att, ker_att);
        wfrag_k<<<512, 256, 0, stream>>>(weight, ch_att, fil_att, sp_att, ker_att, wfrag);
        conv_k<<<2048, 256, 0, stream>>>(xbf, wfrag, out);
    } else {
        pool_partial_k<<<1024, 256, 0, stream>>>(x, part);
        att_k<<<32, 256, 0, stream>>>(part, w_fc, bn_g, bn_b, bn_m, bn_v,
                                      w_ch, b_ch, w_fil, b_fil, w_sp, b_sp, w_ker, b_ker,
                                      ch_att, fil_att, sp_att, ker_att);
        wfrag_k<<<512, 256, 0, stream>>>(weight, ch_att, fil_att, sp_att, ker_att, wfrag);
        conv_fb_k<<<1024, 512, 0, stream>>>(x, wfrag, out);
    }
}

// Round 7
// 134.088 us; speedup vs baseline: 1.0022x; 1.0022x over previous
//
#include <hip/hip_runtime.h>
#include <hip/hip_bf16.h>
#include <stdint.h>

#define B_ 32
#define L_ 4096
#define C_ 256
#define O_ 256
#define K_ 3
#define KN_ 4
#define A_ 16
#define LP_ 4098   // padded rows per batch: p = l+1; p=0 and p=4097 are zero pads

typedef unsigned short u16;
typedef __attribute__((ext_vector_type(8))) short bf16x8;
typedef __attribute__((ext_vector_type(4))) float f32x4;

static __device__ __forceinline__ u16 f2bf(float f) {
    union { float f; uint32_t u; } v; v.f = f;
    uint32_t u = v.u;
    u += 0x7fffu + ((u >> 16) & 1u);   // round-to-nearest-even
    return (u16)(u >> 16);
}

// ---------------- kernel 1: fused pool partials + x -> LINEAR bf16 (padded rows) ----------------
__global__ __launch_bounds__(256) void poolcvt_k(const float* __restrict__ x,
                                                 u16* __restrict__ xb,
                                                 float* __restrict__ part) {
    __shared__ float red[4][256];
    int bid = blockIdx.x;
    int b = bid >> 5, chunk = bid & 31;
    int t = threadIdx.x;
    int w = t >> 6, lane = t & 63;
    int c0 = lane << 2;
    f32x4 s = {0.f, 0.f, 0.f, 0.f};
    const float* xp = x + ((size_t)b * L_ + (size_t)chunk * 128) * C_ + c0;
    u16* xbb = xb + ((size_t)b * LP_ + (size_t)chunk * 128 + 1) * 256;
    #pragma unroll 4
    for (int it = 0; it < 32; ++it) {
        int rl = it * 4 + w;
        float4 v = *reinterpret_cast<const float4*>(xp + (size_t)rl * C_);
        s.x += v.x; s.y += v.y; s.z += v.z; s.w += v.w;
        ushort4 hv;
        hv.x = f2bf(v.x); hv.y = f2bf(v.y); hv.z = f2bf(v.z); hv.w = f2bf(v.w);
        *reinterpret_cast<ushort4*>(xbb + (size_t)rl * 256 + c0) = hv;
    }
    *reinterpret_cast<f32x4*>(&red[w][c0]) = s;
    __syncthreads();
    part[((size_t)bid << 8) + t] = red[0][t] + red[1][t] + red[2][t] + red[3][t];
    if (chunk == 0 && t < 64)
        *reinterpret_cast<ushort4*>(xb + (size_t)b * LP_ * 256 + t * 4) = make_ushort4(0, 0, 0, 0);
    if (chunk == 31 && t < 64)
        *reinterpret_cast<ushort4*>(xb + ((size_t)b * LP_ + LP_ - 1) * 256 + t * 4) = make_ushort4(0, 0, 0, 0);
}

// ---------------- kernel 1 (fallback): pooling partials only ----------------
__global__ __launch_bounds__(256) void pool_partial_k(const float* __restrict__ x,
                                                      float* __restrict__ part) {
    int bid = blockIdx.x;
    int b = bid >> 5, ch = bid & 31;
    int c = threadIdx.x;
    const float* p = x + (size_t)(b * L_ + ch * 128) * C_ + c;
    float s = 0.f;
    #pragma unroll 4
    for (int l = 0; l < 128; ++l) s += p[(size_t)l * C_];
    part[((size_t)bid << 8) + c] = s;
}

// ---------------- kernel 2: attention head (per-batch) ----------------
__global__ __launch_bounds__(256) void att_k(const float* __restrict__ part,
    const float* __restrict__ w_fc, const float* __restrict__ bn_g,
    const float* __restrict__ bn_b, const float* __restrict__ bn_m,
    const float* __restrict__ bn_v,
    const float* __restrict__ w_ch, const float* __restrict__ b_ch,
    const float* __restrict__ w_fil, const float* __restrict__ b_fil,
    const float* __restrict__ w_sp, const float* __restrict__ b_sp,
    const float* __restrict__ w_ker, const float* __restrict__ b_ker,
    float* __restrict__ ch_att, float* __restrict__ fil_att,
    float* __restrict__ sp_att, float* __restrict__ ker_att) {
    __shared__ float pooled[C_];
    __shared__ float h[A_];
    int b = blockIdx.x, t = threadIdx.x;
    float s = 0.f;
    for (int j = 0; j < 32; ++j) s += part[(((size_t)(b * 32 + j)) << 8) + t];
    pooled[t] = s * (1.0f / L_);
    __syncthreads();
    if (t < A_) {
        float acc = 0.f;
        for (int c = 0; c < C_; ++c) acc += pooled[c] * w_fc[t * C_ + c];
        float sc = bn_g[t] * rsqrtf(bn_v[t] + 1e-5f);
        acc = (acc - bn_m[t]) * sc + bn_b[t];
        h[t] = fmaxf(acc, 0.f);
    }
    __syncthreads();
    {
        float a1 = b_ch[t], a2 = b_fil[t];
        for (int a = 0; a < A_; ++a) { a1 += h[a] * w_ch[t * A_ + a]; a2 += h[a] * w_fil[t * A_ + a]; }
        ch_att[b * C_ + t]  = 1.f / (1.f + expf(-a1));
        fil_att[b * O_ + t] = 1.f / (1.f + expf(-a2));
    }
    if (t < K_) {
        float acc = b_sp[t];
        for (int a = 0; a < A_; ++a) acc += h[a] * w_sp[t * A_ + a];
        sp_att[b * 4 + t] = 1.f / (1.f + expf(-acc));
    }
    if (t == 0) {
        float lg[KN_], m = -1e30f;
        for (int n = 0; n < KN_; ++n) {
            float acc = b_ker[n];
            for (int a = 0; a < A_; ++a) acc += h[a] * w_ker[n * A_ + a];
            lg[n] = acc; m = fmaxf(m, acc);
        }
        float ss = 0.f;
        for (int n = 0; n < KN_; ++n) { lg[n] = expf(lg[n] - m); ss += lg[n]; }
        for (int n = 0; n < KN_; ++n) ker_att[b * 4 + n] = lg[n] / ss;
    }
}

// ---------------- kernel 3: effective weights -> bf16 MFMA-fragment layout ----------------
__global__ __launch_bounds__(256) void wfrag_k(const float* __restrict__ weight,
    const float* __restrict__ ch_att, const float* __restrict__ fil_att,
    const float* __restrict__ sp_att, const float* __restrict__ ker_att,
    u16* __restrict__ wf) {
    __shared__ float wlds[64 * 97];
    int beta = blockIdx.x;
    int ob = beta & 15, ic = (beta >> 4) & 7, bg = beta >> 7;
    int t = threadIdx.x;
    const size_t blk_base = (size_t)(ob * 16) * 768 + ic * 96;
    #pragma unroll
    for (int j = 0; j < 24; ++j) {
        int ei = t + (j << 8);
        int r = ei / 96, c = ei - r * 96;
        int n = r >> 4, ol = r & 15;
        wlds[r * 97 + c] = weight[((size_t)n * 256 + ol) * 768 + blk_base + c];
    }
    __syncthreads();
    int lane = t & 63, q = t >> 6;
    int o_l = lane & 15, ig = lane >> 4;
    int i0 = ig << 3;
    int o = (ob << 4) + o_l;
    int ig0 = (ic << 5) + i0;
    float wl[4][3][8];
    #pragma unroll
    for (int n = 0; n < 4; ++n) {
        int rb = (n * 16 + o_l) * 97;
        #pragma unroll
        for (int e = 0; e < 8; ++e) {
            int cb = rb + (i0 + e) * 3;
            wl[n][0][e] = wlds[cb];
            wl[n][1][e] = wlds[cb + 1];
            wl[n][2][e] = wlds[cb + 2];
        }
    }
    #pragma unroll
    for (int bi = 0; bi < 2; ++bi) {
        int b = (bg << 3) + (q << 1) + bi;
        float ka0 = ker_att[b * 4 + 0], ka1 = ker_att[b * 4 + 1];
        float ka2 = ker_att[b * 4 + 2], ka3 = ker_att[b * 4 + 3];
        float fil = fil_att[b * O_ + o];
        float ch8[8];
        *reinterpret_cast<float4*>(ch8)     = *reinterpret_cast<const float4*>(ch_att + b * C_ + ig0);
        *reinterpret_cast<float4*>(ch8 + 4) = *reinterpret_cast<const float4*>(ch_att + b * C_ + ig0 + 4);
        #pragma unroll
        for (int tap = 0; tap < 3; ++tap) {
            float fs = fil * sp_att[b * 4 + tap];
            union { u16 h[8]; uint4 v; } pk;
            #pragma unroll
            for (int e = 0; e < 8; ++e) {
                float acc = ka0 * wl[0][tap][e] + ka1 * wl[1][tap][e]
                          + ka2 * wl[2][tap][e] + ka3 * wl[3][tap][e];
                pk.h[e] = f2bf(acc * fs * ch8[e]);
            }
            size_t idx = ((((size_t)(b * 24 + tap * 8 + ic) * 16 + ob) * 64) + lane) << 3;
            *reinterpret_cast<uint4*>(wf + idx) = pk.v;
        }
    }
}

// ---------------- kernel 4: conv, 4-wave blocks + DEPTH-4 register pipeline ----------------
// grid 2048 (XCD swizzle); block 256 = 4 waves (wr = o-quadrant), l-tile 64.
// LDS: 66 rows x 512 B (33792 B), granule g16 of row r at slot (g16 ^ (r&7)).
__global__ __launch_bounds__(256, 2) void conv_k(const u16* __restrict__ xb,
    const u16* __restrict__ wf, float* __restrict__ out) {
    __shared__ uint4 lds4[2112];               // 33792 B
    char* lp = (char*)lds4;
    int phys = blockIdx.x;
    int logical = ((phys & 7) << 8) + (phys >> 3);   // 2048 = 8 XCD chunks x 256
    int b = logical >> 6, lb = logical & 63;
    int l0 = lb << 6;
    int tid = threadIdx.x;
    const u16* xbb = xb + (size_t)b * LP_ * 256;

    // ---- stage rows p = l0 .. l0+65 (bf16, swizzled ds_write) ----
    #pragma unroll
    for (int it = 0; it < 9; ++it) {
        int id = tid + (it << 8);
        if (id < 2112) {                        // 66 rows * 32 granules
            int r = id >> 5, g16 = id & 31;
            bf16x8 v = *reinterpret_cast<const bf16x8*>(xbb + ((size_t)(l0 + r) << 8) + g16 * 8);
            *reinterpret_cast<bf16x8*>(lp + r * 512 + ((g16 ^ (r & 7)) << 4)) = v;
        }
    }
    __syncthreads();

    int w = tid >> 6, lane = tid & 63;
    int wr = w;                                 // o-quadrant
    int lrow = lane & 15;
    int g = lane >> 4;

    f32x4 acc[4][4] = {};
    const u16* wp0 = wf + ((((size_t)(b * 24) * 16 + wr * 4) * 64 + lane) << 3);

    #define LOAD_AB(AF, BF, kc) do {                                              \
        const int tap_ = (kc) >> 3, ic_ = (kc) & 7;                               \
        _Pragma("unroll")                                                         \
        for (int m = 0; m < 4; ++m)                                               \
            AF[m] = *reinterpret_cast<const bf16x8*>(wp0 + (size_t)(kc) * 8192 + (m << 9)); \
        const int sb_ = (ic_ << 2) + g;                                           \
        _Pragma("unroll")                                                         \
        for (int n = 0; n < 4; ++n) {                                             \
            int row_ = n * 16 + lrow + tap_;                                      \
            BF[n] = *reinterpret_cast<const bf16x8*>(lp + row_ * 512 + ((sb_ ^ (row_ & 7)) << 4)); \
        }                                                                         \
    } while (0)

    #define DO_MFMA(AF, BF) do {                                                  \
        _Pragma("unroll")                                                         \
        for (int m = 0; m < 4; ++m)                                               \
            _Pragma("unroll")                                                     \
            for (int n = 0; n < 4; ++n)                                           \
                acc[m][n] = __builtin_amdgcn_mfma_f32_16x16x32_bf16(AF[m], BF[n], acc[m][n], 0, 0, 0); \
    } while (0)

    bf16x8 af0[4], bf0[4], af1[4], bf1[4], af2[4], bf2[4], af3[4], bf3[4];
    LOAD_AB(af0, bf0, 0);
    LOAD_AB(af1, bf1, 1);
    LOAD_AB(af2, bf2, 2);
    LOAD_AB(af3, bf3, 3);
    #pragma unroll
    for (int k4 = 0; k4 < 6; ++k4) {
        DO_MFMA(af0, bf0);
        if (k4 < 5) LOAD_AB(af0, bf0, k4 * 4 + 4);
        DO_MFMA(af1, bf1);
        if (k4 < 5) LOAD_AB(af1, bf1, k4 * 4 + 5);
        DO_MFMA(af2, bf2);
        if (k4 < 5) LOAD_AB(af2, bf2, k4 * 4 + 6);
        DO_MFMA(af3, bf3);
        if (k4 < 5) LOAD_AB(af3, bf3, k4 * 4 + 7);
    }
    #undef LOAD_AB
    #undef DO_MFMA

    __syncthreads();   // waves done reading x tile; LDS reused below

    // ---- epilogue: per-wave LDS transpose -> 256B-run stores ----
    float* ep = (float*)(lp + w * 8192);
    size_t obase = (size_t)b * O_ * L_;
    #pragma unroll
    for (int c2 = 0; c2 < 2; ++c2) {
        #pragma unroll
        for (int m2 = 0; m2 < 2; ++m2) {
            int m = c2 * 2 + m2;
            #pragma unroll
            for (int n = 0; n < 4; ++n) {
                int l_loc = n * 16 + lrow;
                int sl = (l_loc >> 2);
                #pragma unroll
                for (int j = 0; j < 4; ++j) {
                    int o_loc = m2 * 16 + g * 4 + j;
                    ep[o_loc * 64 + ((sl ^ o_loc) & 15) * 4 + (l_loc & 3)] = acc[m][n][j];
                }
            }
        }
        #pragma unroll
        for (int og = 0; og < 8; ++og) {
            int o_loc = og * 4 + g;
            int l4 = lrow;
            float4 v = *reinterpret_cast<float4*>(ep + o_loc * 64 + ((l4 ^ o_loc) & 15) * 4);
            int o = wr * 64 + c2 * 32 + o_loc;
            *reinterpret_cast<float4*>(out + obase + (size_t)o * L_ + l0 + l4 * 4) = v;
        }
        if (c2 == 0) __syncthreads();
    }
}

// ---------------- kernel 4 (fallback): R2's reg-staged conv from f32 x ----------------
__global__ __launch_bounds__(512, 4) void conv_fb_k(const float* __restrict__ x,
    const u16* __restrict__ wf, float* __restrict__ out) {
    __shared__ uint4 lds4[4160];
    char* lp = (char*)lds4;
    int phys = blockIdx.x;
    int logical = ((phys & 7) << 7) + (phys >> 3);
    int b = logical >> 5, lb = logical & 31;
    int l0 = lb << 7;
    int tid = threadIdx.x;
    const size_t xbase = (size_t)b * L_ * C_;
    #pragma unroll 4
    for (int it = 0; it < 17; ++it) {
        int id = tid + (it << 9);
        if (id < 8320) {
            int r  = id >> 6;
            int i  = (id & 63) << 2;
            int lg = l0 - 1 + r;
            float4 v = make_float4(0.f, 0.f, 0.f, 0.f);
            if (lg >= 0 && lg < L_)
                v = *reinterpret_cast<const float4*>(x + xbase + (size_t)lg * C_ + i);
            ushort4 hv;
            hv.x = f2bf(v.x); hv.y = f2bf(v.y); hv.z = f2bf(v.z); hv.w = f2bf(v.w);
            int slot = (i >> 3) ^ (r & 7);
            int off = r * 512 + slot * 16 + ((i >> 2) & 1) * 8;
            *reinterpret_cast<ushort4*>(lp + off) = hv;
        }
    }
    __syncthreads();
    int w = tid >> 6, lane = tid & 63;
    int wr = w & 3, wc = w >> 2;
    int lrow = lane & 15;
    int g = lane >> 4;
    f32x4 acc[4][4] = {};
    for (int kc = 0; kc < 24; ++kc) {
        int t  = kc >> 3;
        int ic = kc & 7;
        bf16x8 af[4], bfr[4];
        const u16* wp = wf + ((((size_t)(b * 24 + kc) * 16 + wr * 4) * 64 + lane) << 3);
        #pragma unroll
        for (int m = 0; m < 4; ++m)
            af[m] = *reinterpret_cast<const bf16x8*>(wp + (m << 9));
        int slotbase = (ic << 2) + g;
        #pragma unroll
        for (int n = 0; n < 4; ++n) {
            int row = wc * 64 + n * 16 + lrow + t;
            int off = row * 512 + ((slotbase ^ (row & 7)) << 4);
            bfr[n] = *reinterpret_cast<const bf16x8*>(lp + off);
        }
        #pragma unroll
        for (int m = 0; m < 4; ++m)
            #pragma unroll
            for (int n = 0; n < 4; ++n)
                acc[m][n] = __builtin_amdgcn_mfma_f32_16x16x32_bf16(af[m], bfr[n], acc[m][n], 0, 0, 0);
    }
    __syncthreads();
    float* ep = (float*)(lp + w * 8192);
    size_t obase = (size_t)b * O_ * L_;
    int lcol = l0 + wc * 64;
    #pragma unroll
    for (int c2 = 0; c2 < 2; ++c2) {
        #pragma unroll
        for (int m2 = 0; m2 < 2; ++m2) {
            int m = c2 * 2 + m2;
            #pragma unroll
            for (int n = 0; n < 4; ++n) {
                int l_loc = n * 16 + lrow;
                int sl = (l_loc >> 2);
                #pragma unroll
                for (int j = 0; j < 4; ++j) {
                    int o_loc = m2 * 16 + g * 4 + j;
                    ep[o_loc * 64 + ((sl ^ o_loc) & 15) * 4 + (l_loc & 3)] = acc[m][n][j];
                }
            }
        }
        #pragma unroll
        for (int og = 0; og < 8; ++og) {
            int o_loc = og * 4 + g;
            int l4 = lrow;
            float4 v = *reinterpret_cast<float4*>(ep + o_loc * 64 + ((l4 ^ o_loc) & 15) * 4);
            int o = wr * 64 + c2 * 32 + o_loc;
            *reinterpret_cast<float4*>(out + obase + (size_t)o * L_ + lcol + l4 * 4) = v;
        }
        if (c2 == 0) __syncthreads();
    }
}

extern "C" void kernel_launch(void* const* d_in, const int* in_sizes, int n_in,
                              void* d_out, int out_size, void* d_ws, size_t ws_size,
                              hipStream_t stream) {
    const float* x      = (const float*)d_in[0];
    const float* weight = (const float*)d_in[1];
    const float* w_fc   = (const float*)d_in[2];
    const float* bn_g   = (const float*)d_in[3];
    const float* bn_b   = (const float*)d_in[4];
    const float* bn_m   = (const float*)d_in[5];
    const float* bn_v   = (const float*)d_in[6];
    const float* w_ch   = (const float*)d_in[7];
    const float* b_ch   = (const float*)d_in[8];
    const float* w_fil  = (const float*)d_in[9];
    const float* b_fil  = (const float*)d_in[10];
    const float* w_sp   = (const float*)d_in[11];
    const float* b_sp   = (const float*)d_in[12];
    const float* w_ker  = (const float*)d_in[13];
    const float* b_ker  = (const float*)d_in[14];
    float* out = (float*)d_out;
    char*  ws  = (char*)d_ws;

    float* part    = (float*)ws;                         // 1 MB
    float* ch_att  = (float*)(ws + (1 << 20));
    float* fil_att = ch_att + 32 * 256;
    float* sp_att  = fil_att + 32 * 256;
    float* ker_att = sp_att + 32 * 4;
    u16*   wfrag   = (u16*)(ws + (1 << 20) + 70 * 1024); // 12.6 MB
    u16*   xbf     = (u16*)(ws + (16u << 20));           // 32*4098*512 B = 67.1 MB
    const size_t need = (16u << 20) + (size_t)B_ * LP_ * 512;

    if (ws_size >= need) {
        poolcvt_k<<<1024, 256, 0, stream>>>(x, xbf, part);
        att_k<<<32, 256, 0, stream>>>(part, w_fc, bn_g, bn_b, bn_m, bn_v,
                                      w_ch, b_ch, w_fil, b_fil, w_sp, b_sp, w_ker, b_ker,
                                      ch_att, fil_att, sp_att, ker_att);
        wfrag_k<<<512, 256, 0, stream>>>(weight, ch_att, fil_att, sp_att, ker_att, wfrag);
        conv_k<<<2048, 256, 0, stream>>>(xbf, wfrag, out);
    } else {
        pool_partial_k<<<1024, 256, 0, stream>>>(x, part);
        att_k<<<32, 256, 0, stream>>>(part, w_fc, bn_g, bn_b, bn_m, bn_v,
                                      w_ch, b_ch, w_fil, b_fil, w_sp, b_sp, w_ker, b_ker,
                                      ch_att, fil_att, sp_att, ker_att);
        wfrag_k<<<512, 256, 0, stream>>>(weight, ch_att, fil_att, sp_att, ker_att, wfrag);
        conv_fb_k<<<1024, 512, 0, stream>>>(x, wfrag, out);
    }
}

// Round 8
// 121.949 us; speedup vs baseline: 1.1020x; 1.0995x over previous
//
#include <hip/hip_runtime.h>
#include <hip/hip_bf16.h>
#include <stdint.h>

#define B_ 32
#define L_ 4096
#define C_ 256
#define O_ 256
#define K_ 3
#define KN_ 4
#define A_ 16
#define LP_ 4098   // padded rows per batch: p = l+1; p=0 and p=4097 are zero pads

typedef unsigned short u16;
typedef __attribute__((ext_vector_type(8))) short bf16x8;
typedef __attribute__((ext_vector_type(4))) float f32x4;

static __device__ __forceinline__ u16 f2bf(float f) {
    union { float f; uint32_t u; } v; v.f = f;
    uint32_t u = v.u;
    u += 0x7fffu + ((u >> 16) & 1u);   // round-to-nearest-even
    return (u16)(u >> 16);
}

// ---------------- kernel 1: fused pool partials + x -> LINEAR bf16 (padded rows) ----------------
__global__ __launch_bounds__(256) void poolcvt_k(const float* __restrict__ x,
                                                 u16* __restrict__ xb,
                                                 float* __restrict__ part) {
    __shared__ float red[4][256];
    int bid = blockIdx.x;
    int b = bid >> 5, chunk = bid & 31;
    int t = threadIdx.x;
    int w = t >> 6, lane = t & 63;
    int c0 = lane << 2;
    f32x4 s = {0.f, 0.f, 0.f, 0.f};
    const float* xp = x + ((size_t)b * L_ + (size_t)chunk * 128) * C_ + c0;
    u16* xbb = xb + ((size_t)b * LP_ + (size_t)chunk * 128 + 1) * 256;
    #pragma unroll 4
    for (int it = 0; it < 32; ++it) {
        int rl = it * 4 + w;
        float4 v = *reinterpret_cast<const float4*>(xp + (size_t)rl * C_);
        s.x += v.x; s.y += v.y; s.z += v.z; s.w += v.w;
        ushort4 hv;
        hv.x = f2bf(v.x); hv.y = f2bf(v.y); hv.z = f2bf(v.z); hv.w = f2bf(v.w);
        *reinterpret_cast<ushort4*>(xbb + (size_t)rl * 256 + c0) = hv;
    }
    *reinterpret_cast<f32x4*>(&red[w][c0]) = s;
    __syncthreads();
    part[((size_t)bid << 8) + t] = red[0][t] + red[1][t] + red[2][t] + red[3][t];
    if (chunk == 0 && t < 64)
        *reinterpret_cast<ushort4*>(xb + (size_t)b * LP_ * 256 + t * 4) = make_ushort4(0, 0, 0, 0);
    if (chunk == 31 && t < 64)
        *reinterpret_cast<ushort4*>(xb + ((size_t)b * LP_ + LP_ - 1) * 256 + t * 4) = make_ushort4(0, 0, 0, 0);
}

// ---------------- kernel 1 (fallback): pooling partials only ----------------
__global__ __launch_bounds__(256) void pool_partial_k(const float* __restrict__ x,
                                                      float* __restrict__ part) {
    int bid = blockIdx.x;
    int b = bid >> 5, ch = bid & 31;
    int c = threadIdx.x;
    const float* p = x + (size_t)(b * L_ + ch * 128) * C_ + c;
    float s = 0.f;
    #pragma unroll 4
    for (int l = 0; l < 128; ++l) s += p[(size_t)l * C_];
    part[((size_t)bid << 8) + c] = s;
}

// ---------------- kernel 2: attention head (per-batch) ----------------
__global__ __launch_bounds__(256) void att_k(const float* __restrict__ part,
    const float* __restrict__ w_fc, const float* __restrict__ bn_g,
    const float* __restrict__ bn_b, const float* __restrict__ bn_m,
    const float* __restrict__ bn_v,
    const float* __restrict__ w_ch, const float* __restrict__ b_ch,
    const float* __restrict__ w_fil, const float* __restrict__ b_fil,
    const float* __restrict__ w_sp, const float* __restrict__ b_sp,
    const float* __restrict__ w_ker, const float* __restrict__ b_ker,
    float* __restrict__ ch_att, float* __restrict__ fil_att,
    float* __restrict__ sp_att, float* __restrict__ ker_att) {
    __shared__ float pooled[C_];
    __shared__ float h[A_];
    int b = blockIdx.x, t = threadIdx.x;
    float s = 0.f;
    for (int j = 0; j < 32; ++j) s += part[(((size_t)(b * 32 + j)) << 8) + t];
    pooled[t] = s * (1.0f / L_);
    __syncthreads();
    if (t < A_) {
        float acc = 0.f;
        for (int c = 0; c < C_; ++c) acc += pooled[c] * w_fc[t * C_ + c];
        float sc = bn_g[t] * rsqrtf(bn_v[t] + 1e-5f);
        acc = (acc - bn_m[t]) * sc + bn_b[t];
        h[t] = fmaxf(acc, 0.f);
    }
    __syncthreads();
    {
        float a1 = b_ch[t], a2 = b_fil[t];
        for (int a = 0; a < A_; ++a) { a1 += h[a] * w_ch[t * A_ + a]; a2 += h[a] * w_fil[t * A_ + a]; }
        ch_att[b * C_ + t]  = 1.f / (1.f + expf(-a1));
        fil_att[b * O_ + t] = 1.f / (1.f + expf(-a2));
    }
    if (t < K_) {
        float acc = b_sp[t];
        for (int a = 0; a < A_; ++a) acc += h[a] * w_sp[t * A_ + a];
        sp_att[b * 4 + t] = 1.f / (1.f + expf(-acc));
    }
    if (t == 0) {
        float lg[KN_], m = -1e30f;
        for (int n = 0; n < KN_; ++n) {
            float acc = b_ker[n];
            for (int a = 0; a < A_; ++a) acc += h[a] * w_ker[n * A_ + a];
            lg[n] = acc; m = fmaxf(m, acc);
        }
        float ss = 0.f;
        for (int n = 0; n < KN_; ++n) { lg[n] = expf(lg[n] - m); ss += lg[n]; }
        for (int n = 0; n < KN_; ++n) ker_att[b * 4 + n] = lg[n] / ss;
    }
}

// ---------------- kernel 3: effective weights -> bf16 MFMA-fragment layout ----------------
__global__ __launch_bounds__(256) void wfrag_k(const float* __restrict__ weight,
    const float* __restrict__ ch_att, const float* __restrict__ fil_att,
    const float* __restrict__ sp_att, const float* __restrict__ ker_att,
    u16* __restrict__ wf) {
    __shared__ float wlds[64 * 97];
    int beta = blockIdx.x;
    int ob = beta & 15, ic = (beta >> 4) & 7, bg = beta >> 7;
    int t = threadIdx.x;
    const size_t blk_base = (size_t)(ob * 16) * 768 + ic * 96;
    #pragma unroll
    for (int j = 0; j < 24; ++j) {
        int ei = t + (j << 8);
        int r = ei / 96, c = ei - r * 96;
        int n = r >> 4, ol = r & 15;
        wlds[r * 97 + c] = weight[((size_t)n * 256 + ol) * 768 + blk_base + c];
    }
    __syncthreads();
    int lane = t & 63, q = t >> 6;
    int o_l = lane & 15, ig = lane >> 4;
    int i0 = ig << 3;
    int o = (ob << 4) + o_l;
    int ig0 = (ic << 5) + i0;
    float wl[4][3][8];
    #pragma unroll
    for (int n = 0; n < 4; ++n) {
        int rb = (n * 16 + o_l) * 97;
        #pragma unroll
        for (int e = 0; e < 8; ++e) {
            int cb = rb + (i0 + e) * 3;
            wl[n][0][e] = wlds[cb];
            wl[n][1][e] = wlds[cb + 1];
            wl[n][2][e] = wlds[cb + 2];
        }
    }
    #pragma unroll
    for (int bi = 0; bi < 2; ++bi) {
        int b = (bg << 3) + (q << 1) + bi;
        float ka0 = ker_att[b * 4 + 0], ka1 = ker_att[b * 4 + 1];
        float ka2 = ker_att[b * 4 + 2], ka3 = ker_att[b * 4 + 3];
        float fil = fil_att[b * O_ + o];
        float ch8[8];
        *reinterpret_cast<float4*>(ch8)     = *reinterpret_cast<const float4*>(ch_att + b * C_ + ig0);
        *reinterpret_cast<float4*>(ch8 + 4) = *reinterpret_cast<const float4*>(ch_att + b * C_ + ig0 + 4);
        #pragma unroll
        for (int tap = 0; tap < 3; ++tap) {
            float fs = fil * sp_att[b * 4 + tap];
            union { u16 h[8]; uint4 v; } pk;
            #pragma unroll
            for (int e = 0; e < 8; ++e) {
                float acc = ka0 * wl[0][tap][e] + ka1 * wl[1][tap][e]
                          + ka2 * wl[2][tap][e] + ka3 * wl[3][tap][e];
                pk.h[e] = f2bf(acc * fs * ch8[e]);
            }
            size_t idx = ((((size_t)(b * 24 + tap * 8 + ic) * 16 + ob) * 64) + lane) << 3;
            *reinterpret_cast<uint4*>(wf + idx) = pk.v;
        }
    }
}

// ---------------- kernel 4: conv, 32o-wave / 4-blocks-per-CU TLP version ----------------
// grid 4096 (XCD swizzle); block 256 = 4 waves; wave = 32 o x 64 l; block = 128 o x 64 l.
// LDS: 66 rows x 512 B (33792 B), granule g16 of row r at slot (g16 ^ (r&7)).
__global__ __launch_bounds__(256, 4) void conv_k(const u16* __restrict__ xb,
    const u16* __restrict__ wf, float* __restrict__ out) {
    __shared__ uint4 lds4[2112];               // 33792 B
    char* lp = (char*)lds4;
    int phys = blockIdx.x;
    int logical = ((phys & 7) << 9) + (phys >> 3);   // 4096 = 8 XCD chunks x 512
    int b = logical >> 7;
    int lb = (logical >> 1) & 63;
    int oh = logical & 1;                      // o-half: paired blocks share the x tile
    int l0 = lb << 6;
    int tid = threadIdx.x;
    const u16* xbb = xb + (size_t)b * LP_ * 256;

    // ---- stage rows p = l0 .. l0+65 (bf16, swizzled ds_write) ----
    #pragma unroll
    for (int it = 0; it < 9; ++it) {
        int id = tid + (it << 8);
        if (id < 2112) {                        // 66 rows * 32 granules
            int r = id >> 5, g16 = id & 31;
            bf16x8 v = *reinterpret_cast<const bf16x8*>(xbb + ((size_t)(l0 + r) << 8) + g16 * 8);
            *reinterpret_cast<bf16x8*>(lp + r * 512 + ((g16 ^ (r & 7)) << 4)) = v;
        }
    }
    __syncthreads();

    int w = tid >> 6, lane = tid & 63;
    int lrow = lane & 15;
    int g = lane >> 4;
    int o0 = oh * 128 + w * 32;                // wave's o base
    int ob0 = oh * 8 + w * 2;                  // wf 16-o block index base

    f32x4 acc[2][4] = {};
    const u16* wp0 = wf + ((((size_t)(b * 24) * 16 + ob0) * 64 + lane) << 3);

    #define LOAD_AB(AF, BF, kc) do {                                              \
        const int tap_ = (kc) >> 3, ic_ = (kc) & 7;                               \
        _Pragma("unroll")                                                         \
        for (int m = 0; m < 2; ++m)                                               \
            AF[m] = *reinterpret_cast<const bf16x8*>(wp0 + (size_t)(kc) * 8192 + (m << 9)); \
        const int sb_ = (ic_ << 2) + g;                                           \
        _Pragma("unroll")                                                         \
        for (int n = 0; n < 4; ++n) {                                             \
            int row_ = n * 16 + lrow + tap_;                                      \
            BF[n] = *reinterpret_cast<const bf16x8*>(lp + row_ * 512 + ((sb_ ^ (row_ & 7)) << 4)); \
        }                                                                         \
    } while (0)

    #define DO_MFMA(AF, BF) do {                                                  \
        _Pragma("unroll")                                                         \
        for (int m = 0; m < 2; ++m)                                               \
            _Pragma("unroll")                                                     \
            for (int n = 0; n < 4; ++n)                                           \
                acc[m][n] = __builtin_amdgcn_mfma_f32_16x16x32_bf16(AF[m], BF[n], acc[m][n], 0, 0, 0); \
    } while (0)

    bf16x8 afA[2], bfA[4], afB[2], bfB[4];
    LOAD_AB(afA, bfA, 0);
    LOAD_AB(afB, bfB, 1);
    #pragma unroll
    for (int kc2 = 0; kc2 < 12; ++kc2) {
        DO_MFMA(afA, bfA);
        if (kc2 < 11) LOAD_AB(afA, bfA, 2 * kc2 + 2);
        DO_MFMA(afB, bfB);
        if (kc2 < 11) LOAD_AB(afB, bfB, 2 * kc2 + 3);
    }
    #undef LOAD_AB
    #undef DO_MFMA

    __syncthreads();   // waves done reading x tile; LDS reused below

    // ---- epilogue: per-wave LDS transpose (32 o x 64 l, 8 KB) -> 256B-run stores ----
    float* ep = (float*)(lp + w * 8192);
    size_t obase = (size_t)b * O_ * L_;
    #pragma unroll
    for (int m2 = 0; m2 < 2; ++m2) {
        #pragma unroll
        for (int n = 0; n < 4; ++n) {
            int l_loc = n * 16 + lrow;
            int sl = (l_loc >> 2);
            #pragma unroll
            for (int j = 0; j < 4; ++j) {
                int o_loc = m2 * 16 + g * 4 + j;
                ep[o_loc * 64 + ((sl ^ o_loc) & 15) * 4 + (l_loc & 3)] = acc[m2][n][j];
            }
        }
    }
    #pragma unroll
    for (int og = 0; og < 8; ++og) {
        int o_loc = og * 4 + g;
        int l4 = lrow;
        float4 v = *reinterpret_cast<float4*>(ep + o_loc * 64 + ((l4 ^ o_loc) & 15) * 4);
        int o = o0 + o_loc;
        *reinterpret_cast<float4*>(out + obase + (size_t)o * L_ + l0 + l4 * 4) = v;
    }
}

// ---------------- kernel 4 (fallback): R2's reg-staged conv from f32 x ----------------
__global__ __launch_bounds__(512, 4) void conv_fb_k(const float* __restrict__ x,
    const u16* __restrict__ wf, float* __restrict__ out) {
    __shared__ uint4 lds4[4160];
    char* lp = (char*)lds4;
    int phys = blockIdx.x;
    int logical = ((phys & 7) << 7) + (phys >> 3);
    int b = logical >> 5, lb = logical & 31;
    int l0 = lb << 7;
    int tid = threadIdx.x;
    const size_t xbase = (size_t)b * L_ * C_;
    #pragma unroll 4
    for (int it = 0; it < 17; ++it) {
        int id = tid + (it << 9);
        if (id < 8320) {
            int r  = id >> 6;
            int i  = (id & 63) << 2;
            int lg = l0 - 1 + r;
            float4 v = make_float4(0.f, 0.f, 0.f, 0.f);
            if (lg >= 0 && lg < L_)
                v = *reinterpret_cast<const float4*>(x + xbase + (size_t)lg * C_ + i);
            ushort4 hv;
            hv.x = f2bf(v.x); hv.y = f2bf(v.y); hv.z = f2bf(v.z); hv.w = f2bf(v.w);
            int slot = (i >> 3) ^ (r & 7);
            int off = r * 512 + slot * 16 + ((i >> 2) & 1) * 8;
            *reinterpret_cast<ushort4*>(lp + off) = hv;
        }
    }
    __syncthreads();
    int w = tid >> 6, lane = tid & 63;
    int wr = w & 3, wc = w >> 2;
    int lrow = lane & 15;
    int g = lane >> 4;
    f32x4 acc[4][4] = {};
    for (int kc = 0; kc < 24; ++kc) {
        int t  = kc >> 3;
        int ic = kc & 7;
        bf16x8 af[4], bfr[4];
        const u16* wp = wf + ((((size_t)(b * 24 + kc) * 16 + wr * 4) * 64 + lane) << 3);
        #pragma unroll
        for (int m = 0; m < 4; ++m)
            af[m] = *reinterpret_cast<const bf16x8*>(wp + (m << 9));
        int slotbase = (ic << 2) + g;
        #pragma unroll
        for (int n = 0; n < 4; ++n) {
            int row = wc * 64 + n * 16 + lrow + t;
            int off = row * 512 + ((slotbase ^ (row & 7)) << 4);
            bfr[n] = *reinterpret_cast<const bf16x8*>(lp + off);
        }
        #pragma unroll
        for (int m = 0; m < 4; ++m)
            #pragma unroll
            for (int n = 0; n < 4; ++n)
                acc[m][n] = __builtin_amdgcn_mfma_f32_16x16x32_bf16(af[m], bfr[n], acc[m][n], 0, 0, 0);
    }
    __syncthreads();
    float* ep = (float*)(lp + w * 8192);
    size_t obase = (size_t)b * O_ * L_;
    int lcol = l0 + wc * 64;
    #pragma unroll
    for (int c2 = 0; c2 < 2; ++c2) {
        #pragma unroll
        for (int m2 = 0; m2 < 2; ++m2) {
            int m = c2 * 2 + m2;
            #pragma unroll
            for (int n = 0; n < 4; ++n) {
                int l_loc = n * 16 + lrow;
                int sl = (l_loc >> 2);
                #pragma unroll
                for (int j = 0; j < 4; ++j) {
                    int o_loc = m2 * 16 + g * 4 + j;
                    ep[o_loc * 64 + ((sl ^ o_loc) & 15) * 4 + (l_loc & 3)] = acc[m][n][j];
                }
            }
        }
        #pragma unroll
        for (int og = 0; og < 8; ++og) {
            int o_loc = og * 4 + g;
            int l4 = lrow;
            float4 v = *reinterpret_cast<float4*>(ep + o_loc * 64 + ((l4 ^ o_loc) & 15) * 4);
            int o = wr * 64 + c2 * 32 + o_loc;
            *reinterpret_cast<float4*>(out + obase + (size_t)o * L_ + lcol + l4 * 4) = v;
        }
        if (c2 == 0) __syncthreads();
    }
}

extern "C" void kernel_launch(void* const* d_in, const int* in_sizes, int n_in,
                              void* d_out, int out_size, void* d_ws, size_t ws_size,
                              hipStream_t stream) {
    const float* x      = (const float*)d_in[0];
    const float* weight = (const float*)d_in[1];
    const float* w_fc   = (const float*)d_in[2];
    const float* bn_g   = (const float*)d_in[3];
    const float* bn_b   = (const float*)d_in[4];
    const float* bn_m   = (const float*)d_in[5];
    const float* bn_v   = (const float*)d_in[6];
    const float* w_ch   = (const float*)d_in[7];
    const float* b_ch   = (const float*)d_in[8];
    const float* w_fil  = (const float*)d_in[9];
    const float* b_fil  = (const float*)d_in[10];
    const float* w_sp   = (const float*)d_in[11];
    const float* b_sp   = (const float*)d_in[12];
    const float* w_ker  = (const float*)d_in[13];
    const float* b_ker  = (const float*)d_in[14];
    float* out = (float*)d_out;
    char*  ws  = (char*)d_ws;

    float* part    = (float*)ws;                         // 1 MB
    float* ch_att  = (float*)(ws + (1 << 20));
    float* fil_att = ch_att + 32 * 256;
    float* sp_att  = fil_att + 32 * 256;
    float* ker_att = sp_att + 32 * 4;
    u16*   wfrag   = (u16*)(ws + (1 << 20) + 70 * 1024); // 12.6 MB
    u16*   xbf     = (u16*)(ws + (16u << 20));           // 32*4098*512 B = 67.1 MB
    const size_t need = (16u << 20) + (size_t)B_ * LP_ * 512;

    if (ws_size >= need) {
        poolcvt_k<<<1024, 256, 0, stream>>>(x, xbf, part);
        att_k<<<32, 256, 0, stream>>>(part, w_fc, bn_g, bn_b, bn_m, bn_v,
                                      w_ch, b_ch, w_fil, b_fil, w_sp, b_sp, w_ker, b_ker,
                                      ch_att, fil_att, sp_att, ker_att);
        wfrag_k<<<512, 256, 0, stream>>>(weight, ch_att, fil_att, sp_att, ker_att, wfrag);
        conv_k<<<4096, 256, 0, stream>>>(xbf, wfrag, out);
    } else {
        pool_partial_k<<<1024, 256, 0, stream>>>(x, part);
        att_k<<<32, 256, 0, stream>>>(part, w_fc, bn_g, bn_b, bn_m, bn_v,
                                      w_ch, b_ch, w_fil, b_fil, w_sp, b_sp, w_ker, b_ker,
                                      ch_att, fil_att, sp_att, ker_att);
        wfrag_k<<<512, 256, 0, stream>>>(weight, ch_att, fil_att, sp_att, ker_att, wfrag);
        conv_fb_k<<<1024, 512, 0, stream>>>(x, wfrag, out);
    }
}

// Round 9
// 118.148 us; speedup vs baseline: 1.1375x; 1.0322x over previous
//
#include <hip/hip_runtime.h>
#include <hip/hip_bf16.h>
#include <stdint.h>

#define B_ 32
#define L_ 4096
#define C_ 256
#define O_ 256
#define K_ 3
#define KN_ 4
#define A_ 16
#define LP_ 4098   // padded rows per batch: p = l+1; p=0 and p=4097 are zero pads

typedef unsigned short u16;
typedef __attribute__((ext_vector_type(8))) short bf16x8;
typedef __attribute__((ext_vector_type(4))) float f32x4;

static __device__ __forceinline__ u16 f2bf(float f) {
    union { float f; uint32_t u; } v; v.f = f;
    uint32_t u = v.u;
    u += 0x7fffu + ((u >> 16) & 1u);   // round-to-nearest-even
    return (u16)(u >> 16);
}

// ---------------- kernel 1: fused pool partials + x -> LINEAR bf16 (padded rows) ----------------
__global__ __launch_bounds__(256) void poolcvt_k(const float* __restrict__ x,
                                                 u16* __restrict__ xb,
                                                 float* __restrict__ part) {
    __shared__ float red[4][256];
    int bid = blockIdx.x;
    int b = bid >> 5, chunk = bid & 31;
    int t = threadIdx.x;
    int w = t >> 6, lane = t & 63;
    int c0 = lane << 2;
    f32x4 s = {0.f, 0.f, 0.f, 0.f};
    const float* xp = x + ((size_t)b * L_ + (size_t)chunk * 128) * C_ + c0;
    u16* xbb = xb + ((size_t)b * LP_ + (size_t)chunk * 128 + 1) * 256;
    #pragma unroll 4
    for (int it = 0; it < 32; ++it) {
        int rl = it * 4 + w;
        float4 v = *reinterpret_cast<const float4*>(xp + (size_t)rl * C_);
        s.x += v.x; s.y += v.y; s.z += v.z; s.w += v.w;
        ushort4 hv;
        hv.x = f2bf(v.x); hv.y = f2bf(v.y); hv.z = f2bf(v.z); hv.w = f2bf(v.w);
        *reinterpret_cast<ushort4*>(xbb + (size_t)rl * 256 + c0) = hv;
    }
    *reinterpret_cast<f32x4*>(&red[w][c0]) = s;
    __syncthreads();
    part[((size_t)bid << 8) + t] = red[0][t] + red[1][t] + red[2][t] + red[3][t];
    if (chunk == 0 && t < 64)
        *reinterpret_cast<ushort4*>(xb + (size_t)b * LP_ * 256 + t * 4) = make_ushort4(0, 0, 0, 0);
    if (chunk == 31 && t < 64)
        *reinterpret_cast<ushort4*>(xb + ((size_t)b * LP_ + LP_ - 1) * 256 + t * 4) = make_ushort4(0, 0, 0, 0);
}

// ---------------- kernel 1 (fallback): pooling partials only ----------------
__global__ __launch_bounds__(256) void pool_partial_k(const float* __restrict__ x,
                                                      float* __restrict__ part) {
    int bid = blockIdx.x;
    int b = bid >> 5, ch = bid & 31;
    int c = threadIdx.x;
    const float* p = x + (size_t)(b * L_ + ch * 128) * C_ + c;
    float s = 0.f;
    #pragma unroll 4
    for (int l = 0; l < 128; ++l) s += p[(size_t)l * C_];
    part[((size_t)bid << 8) + c] = s;
}

// ---------------- kernel 2: attention head (per-batch) ----------------
__global__ __launch_bounds__(256) void att_k(const float* __restrict__ part,
    const float* __restrict__ w_fc, const float* __restrict__ bn_g,
    const float* __restrict__ bn_b, const float* __restrict__ bn_m,
    const float* __restrict__ bn_v,
    const float* __restrict__ w_ch, const float* __restrict__ b_ch,
    const float* __restrict__ w_fil, const float* __restrict__ b_fil,
    const float* __restrict__ w_sp, const float* __restrict__ b_sp,
    const float* __restrict__ w_ker, const float* __restrict__ b_ker,
    float* __restrict__ ch_att, float* __restrict__ fil_att,
    float* __restrict__ sp_att, float* __restrict__ ker_att) {
    __shared__ float pooled[C_];
    __shared__ float h[A_];
    int b = blockIdx.x, t = threadIdx.x;
    float s = 0.f;
    for (int j = 0; j < 32; ++j) s += part[(((size_t)(b * 32 + j)) << 8) + t];
    pooled[t] = s * (1.0f / L_);
    __syncthreads();
    if (t < A_) {
        float acc = 0.f;
        for (int c = 0; c < C_; ++c) acc += pooled[c] * w_fc[t * C_ + c];
        float sc = bn_g[t] * rsqrtf(bn_v[t] + 1e-5f);
        acc = (acc - bn_m[t]) * sc + bn_b[t];
        h[t] = fmaxf(acc, 0.f);
    }
    __syncthreads();
    {
        float a1 = b_ch[t], a2 = b_fil[t];
        for (int a = 0; a < A_; ++a) { a1 += h[a] * w_ch[t * A_ + a]; a2 += h[a] * w_fil[t * A_ + a]; }
        ch_att[b * C_ + t]  = 1.f / (1.f + expf(-a1));
        fil_att[b * O_ + t] = 1.f / (1.f + expf(-a2));
    }
    if (t < K_) {
        float acc = b_sp[t];
        for (int a = 0; a < A_; ++a) acc += h[a] * w_sp[t * A_ + a];
        sp_att[b * 4 + t] = 1.f / (1.f + expf(-acc));
    }
    if (t == 0) {
        float lg[KN_], m = -1e30f;
        for (int n = 0; n < KN_; ++n) {
            float acc = b_ker[n];
            for (int a = 0; a < A_; ++a) acc += h[a] * w_ker[n * A_ + a];
            lg[n] = acc; m = fmaxf(m, acc);
        }
        float ss = 0.f;
        for (int n = 0; n < KN_; ++n) { lg[n] = expf(lg[n] - m); ss += lg[n]; }
        for (int n = 0; n < KN_; ++n) ker_att[b * 4 + n] = lg[n] / ss;
    }
}

// ---------------- kernel 3: effective weights -> bf16 MFMA-fragment layout ----------------
__global__ __launch_bounds__(256) void wfrag_k(const float* __restrict__ weight,
    const float* __restrict__ ch_att, const float* __restrict__ fil_att,
    const float* __restrict__ sp_att, const float* __restrict__ ker_att,
    u16* __restrict__ wf) {
    __shared__ float wlds[64 * 97];
    int beta = blockIdx.x;
    int ob = beta & 15, ic = (beta >> 4) & 7, bg = beta >> 7;
    int t = threadIdx.x;
    const size_t blk_base = (size_t)(ob * 16) * 768 + ic * 96;
    #pragma unroll
    for (int j = 0; j < 24; ++j) {
        int ei = t + (j << 8);
        int r = ei / 96, c = ei - r * 96;
        int n = r >> 4, ol = r & 15;
        wlds[r * 97 + c] = weight[((size_t)n * 256 + ol) * 768 + blk_base + c];
    }
    __syncthreads();
    int lane = t & 63, q = t >> 6;
    int o_l = lane & 15, ig = lane >> 4;
    int i0 = ig << 3;
    int o = (ob << 4) + o_l;
    int ig0 = (ic << 5) + i0;
    float wl[4][3][8];
    #pragma unroll
    for (int n = 0; n < 4; ++n) {
        int rb = (n * 16 + o_l) * 97;
        #pragma unroll
        for (int e = 0; e < 8; ++e) {
            int cb = rb + (i0 + e) * 3;
            wl[n][0][e] = wlds[cb];
            wl[n][1][e] = wlds[cb + 1];
            wl[n][2][e] = wlds[cb + 2];
        }
    }
    #pragma unroll
    for (int bi = 0; bi < 2; ++bi) {
        int b = (bg << 3) + (q << 1) + bi;
        float ka0 = ker_att[b * 4 + 0], ka1 = ker_att[b * 4 + 1];
        float ka2 = ker_att[b * 4 + 2], ka3 = ker_att[b * 4 + 3];
        float fil = fil_att[b * O_ + o];
        float ch8[8];
        *reinterpret_cast<float4*>(ch8)     = *reinterpret_cast<const float4*>(ch_att + b * C_ + ig0);
        *reinterpret_cast<float4*>(ch8 + 4) = *reinterpret_cast<const float4*>(ch_att + b * C_ + ig0 + 4);
        #pragma unroll
        for (int tap = 0; tap < 3; ++tap) {
            float fs = fil * sp_att[b * 4 + tap];
            union { u16 h[8]; uint4 v; } pk;
            #pragma unroll
            for (int e = 0; e < 8; ++e) {
                float acc = ka0 * wl[0][tap][e] + ka1 * wl[1][tap][e]
                          + ka2 * wl[2][tap][e] + ka3 * wl[3][tap][e];
                pk.h[e] = f2bf(acc * fs * ch8[e]);
            }
            size_t idx = ((((size_t)(b * 24 + tap * 8 + ic) * 16 + ob) * 64) + lane) << 3;
            *reinterpret_cast<uint4*>(wf + idx) = pk.v;
        }
    }
}

// ---------------- kernel 4: conv, asm-pipelined K-loop (counted vmcnt/lgkmcnt) ----------------
// grid 2048 (XCD swizzle); block 256 = 4 waves (wr = o-quadrant), wave 64o x 64l.
// LDS: 66 rows x 512 B (33792 B), granule g16 of row r at slot (g16 ^ (r&7)).
// K-loop: depth-2 asm double-buffer for A (global) and B (LDS); waits never drain to 0
// until the final iteration; no compiler memory ops inside the loop.
__global__ __launch_bounds__(256, 3) void conv_k(const u16* __restrict__ xb,
    const u16* __restrict__ wf, float* __restrict__ out) {
    __shared__ uint4 lds4[2112];               // 33792 B
    char* lp = (char*)lds4;
    int phys = blockIdx.x;
    int logical = ((phys & 7) << 8) + (phys >> 3);   // 2048 = 8 XCD chunks x 256
    int b = logical >> 6, lb = logical & 63;
    int l0 = lb << 6;
    int tid = threadIdx.x;
    const u16* xbb = xb + (size_t)b * LP_ * 256;

    // ---- stage rows p = l0 .. l0+65 (bf16, swizzled ds_write) ----
    #pragma unroll
    for (int it = 0; it < 9; ++it) {
        int id = tid + (it << 8);
        if (id < 2112) {                        // 66 rows * 32 granules
            int r = id >> 5, g16 = id & 31;
            bf16x8 v = *reinterpret_cast<const bf16x8*>(xbb + ((size_t)(l0 + r) << 8) + g16 * 8);
            *reinterpret_cast<bf16x8*>(lp + r * 512 + ((g16 ^ (r & 7)) << 4)) = v;
        }
    }
    __syncthreads();   // compiler drains vmcnt/lgkmcnt to 0 here -> clean counter baseline

    int w = tid >> 6, lane = tid & 63;
    int wr = w;                                 // o-quadrant
    int lrow = lane & 15;
    int g = lane >> 4;

    f32x4 acc[4][4] = {};
    const u16* wp0 = wf + ((((size_t)(b * 24) * 16 + wr * 4) * 64 + lane) << 3);
    uint32_t lds_base = (uint32_t)(uintptr_t)(__attribute__((address_space(3))) char*)lp;

    // issue A(kc): 4 global_load_dwordx4 ; B(kc): 4 ds_read_b128  (asm, in-order)
    #define ISSUE_AB(AF, BF, kc_) do {                                             \
        const u16* pa_ = wp0 + (size_t)(kc_) * 8192;                               \
        asm volatile("global_load_dwordx4 %0, %1, off"             : "=v"(AF[0]) : "v"(pa_)); \
        asm volatile("global_load_dwordx4 %0, %1, off offset:1024" : "=v"(AF[1]) : "v"(pa_)); \
        asm volatile("global_load_dwordx4 %0, %1, off offset:2048" : "=v"(AF[2]) : "v"(pa_)); \
        asm volatile("global_load_dwordx4 %0, %1, off offset:3072" : "=v"(AF[3]) : "v"(pa_)); \
        const int tap_ = (kc_) >> 3, ic_ = (kc_) & 7;                              \
        const int r0_ = lrow + tap_;                                               \
        uint32_t vb_ = lds_base + r0_ * 512 + (((((ic_) << 2) + g) ^ (r0_ & 7)) << 4); \
        asm volatile("ds_read_b128 %0, %1"              : "=v"(BF[0]) : "v"(vb_)); \
        asm volatile("ds_read_b128 %0, %1 offset:8192"  : "=v"(BF[1]) : "v"(vb_)); \
        asm volatile("ds_read_b128 %0, %1 offset:16384" : "=v"(BF[2]) : "v"(vb_)); \
        asm volatile("ds_read_b128 %0, %1 offset:24576" : "=v"(BF[3]) : "v"(vb_)); \
    } while (0)

    #define DO_MFMA(AF, BF) do {                                                  \
        _Pragma("unroll")                                                         \
        for (int m = 0; m < 4; ++m)                                               \
            _Pragma("unroll")                                                     \
            for (int n = 0; n < 4; ++n)                                           \
                acc[m][n] = __builtin_amdgcn_mfma_f32_16x16x32_bf16(AF[m], BF[n], acc[m][n], 0, 0, 0); \
    } while (0)

    bf16x8 aA[4], bA[4], aB[4], bB[4];
    ISSUE_AB(aA, bA, 0);
    ISSUE_AB(aB, bB, 1);
    #pragma unroll
    for (int kc = 0; kc < 24; ++kc) {
        if (kc < 23) asm volatile("s_waitcnt vmcnt(4) lgkmcnt(4)");
        else         asm volatile("s_waitcnt vmcnt(0) lgkmcnt(0)");
        __builtin_amdgcn_sched_barrier(0);     // nothing below the wait may hoist above it
        __builtin_amdgcn_s_setprio(1);
        if (kc & 1) DO_MFMA(aB, bB); else DO_MFMA(aA, bA);
        __builtin_amdgcn_s_setprio(0);
        if (kc < 22) {                          // refill the buffer just consumed
            if (kc & 1) ISSUE_AB(aB, bB, kc + 2);
            else        ISSUE_AB(aA, bA, kc + 2);
        }
        __builtin_amdgcn_sched_barrier(0);
    }
    #undef ISSUE_AB
    #undef DO_MFMA

    __syncthreads();   // waves done reading x tile; LDS reused below

    // ---- epilogue: per-wave LDS transpose -> 256B-run stores ----
    float* ep = (float*)(lp + w * 8192);
    size_t obase = (size_t)b * O_ * L_;
    #pragma unroll
    for (int c2 = 0; c2 < 2; ++c2) {
        #pragma unroll
        for (int m2 = 0; m2 < 2; ++m2) {
            int m = c2 * 2 + m2;
            #pragma unroll
            for (int n = 0; n < 4; ++n) {
                int l_loc = n * 16 + lrow;
                int sl = (l_loc >> 2);
                #pragma unroll
                for (int j = 0; j < 4; ++j) {
                    int o_loc = m2 * 16 + g * 4 + j;
                    ep[o_loc * 64 + ((sl ^ o_loc) & 15) * 4 + (l_loc & 3)] = acc[m][n][j];
                }
            }
        }
        #pragma unroll
        for (int og = 0; og < 8; ++og) {
            int o_loc = og * 4 + g;
            int l4 = lrow;
            float4 v = *reinterpret_cast<float4*>(ep + o_loc * 64 + ((l4 ^ o_loc) & 15) * 4);
            int o = wr * 64 + c2 * 32 + o_loc;
            *reinterpret_cast<float4*>(out + obase + (size_t)o * L_ + l0 + l4 * 4) = v;
        }
        if (c2 == 0) __syncthreads();
    }
}

// ---------------- kernel 4 (fallback): R2's reg-staged conv from f32 x ----------------
__global__ __launch_bounds__(512, 4) void conv_fb_k(const float* __restrict__ x,
    const u16* __restrict__ wf, float* __restrict__ out) {
    __shared__ uint4 lds4[4160];
    char* lp = (char*)lds4;
    int phys = blockIdx.x;
    int logical = ((phys & 7) << 7) + (phys >> 3);
    int b = logical >> 5, lb = logical & 31;
    int l0 = lb << 7;
    int tid = threadIdx.x;
    const size_t xbase = (size_t)b * L_ * C_;
    #pragma unroll 4
    for (int it = 0; it < 17; ++it) {
        int id = tid + (it << 9);
        if (id < 8320) {
            int r  = id >> 6;
            int i  = (id & 63) << 2;
            int lg = l0 - 1 + r;
            float4 v = make_float4(0.f, 0.f, 0.f, 0.f);
            if (lg >= 0 && lg < L_)
                v = *reinterpret_cast<const float4*>(x + xbase + (size_t)lg * C_ + i);
            ushort4 hv;
            hv.x = f2bf(v.x); hv.y = f2bf(v.y); hv.z = f2bf(v.z); hv.w = f2bf(v.w);
            int slot = (i >> 3) ^ (r & 7);
            int off = r * 512 + slot * 16 + ((i >> 2) & 1) * 8;
            *reinterpret_cast<ushort4*>(lp + off) = hv;
        }
    }
    __syncthreads();
    int w = tid >> 6, lane = tid & 63;
    int wr = w & 3, wc = w >> 2;
    int lrow = lane & 15;
    int g = lane >> 4;
    f32x4 acc[4][4] = {};
    for (int kc = 0; kc < 24; ++kc) {
        int t  = kc >> 3;
        int ic = kc & 7;
        bf16x8 af[4], bfr[4];
        const u16* wp = wf + ((((size_t)(b * 24 + kc) * 16 + wr * 4) * 64 + lane) << 3);
        #pragma unroll
        for (int m = 0; m < 4; ++m)
            af[m] = *reinterpret_cast<const bf16x8*>(wp + (m << 9));
        int slotbase = (ic << 2) + g;
        #pragma unroll
        for (int n = 0; n < 4; ++n) {
            int row = wc * 64 + n * 16 + lrow + t;
            int off = row * 512 + ((slotbase ^ (row & 7)) << 4);
            bfr[n] = *reinterpret_cast<const bf16x8*>(lp + off);
        }
        #pragma unroll
        for (int m = 0; m < 4; ++m)
            #pragma unroll
            for (int n = 0; n < 4; ++n)
                acc[m][n] = __builtin_amdgcn_mfma_f32_16x16x32_bf16(af[m], bfr[n], acc[m][n], 0, 0, 0);
    }
    __syncthreads();
    float* ep = (float*)(lp + w * 8192);
    size_t obase = (size_t)b * O_ * L_;
    int lcol = l0 + wc * 64;
    #pragma unroll
    for (int c2 = 0; c2 < 2; ++c2) {
        #pragma unroll
        for (int m2 = 0; m2 < 2; ++m2) {
            int m = c2 * 2 + m2;
            #pragma unroll
            for (int n = 0; n < 4; ++n) {
                int l_loc = n * 16 + lrow;
                int sl = (l_loc >> 2);
                #pragma unroll
                for (int j = 0; j < 4; ++j) {
                    int o_loc = m2 * 16 + g * 4 + j;
                    ep[o_loc * 64 + ((sl ^ o_loc) & 15) * 4 + (l_loc & 3)] = acc[m][n][j];
                }
            }
        }
        #pragma unroll
        for (int og = 0; og < 8; ++og) {
            int o_loc = og * 4 + g;
            int l4 = lrow;
            float4 v = *reinterpret_cast<float4*>(ep + o_loc * 64 + ((l4 ^ o_loc) & 15) * 4);
            int o = wr * 64 + c2 * 32 + o_loc;
            *reinterpret_cast<float4*>(out + obase + (size_t)o * L_ + lcol + l4 * 4) = v;
        }
        if (c2 == 0) __syncthreads();
    }
}

extern "C" void kernel_launch(void* const* d_in, const int* in_sizes, int n_in,
                              void* d_out, int out_size, void* d_ws, size_t ws_size,
                              hipStream_t stream) {
    const float* x      = (const float*)d_in[0];
    const float* weight = (const float*)d_in[1];
    const float* w_fc   = (const float*)d_in[2];
    const float* bn_g   = (const float*)d_in[3];
    const float* bn_b   = (const float*)d_in[4];
    const float* bn_m   = (const float*)d_in[5];
    const float* bn_v   = (const float*)d_in[6];
    const float* w_ch   = (const float*)d_in[7];
    const float* b_ch   = (const float*)d_in[8];
    const float* w_fil  = (const float*)d_in[9];
    const float* b_fil  = (const float*)d_in[10];
    const float* w_sp   = (const float*)d_in[11];
    const float* b_sp   = (const float*)d_in[12];
    const float* w_ker  = (const float*)d_in[13];
    const float* b_ker  = (const float*)d_in[14];
    float* out = (float*)d_out;
    char*  ws  = (char*)d_ws;

    float* part    = (float*)ws;                         // 1 MB
    float* ch_att  = (float*)(ws + (1 << 20));
    float* fil_att = ch_att + 32 * 256;
    float* sp_att  = fil_att + 32 * 256;
    float* ker_att = sp_att + 32 * 4;
    u16*   wfrag   = (u16*)(ws + (1 << 20) + 70 * 1024); // 12.6 MB
    u16*   xbf     = (u16*)(ws + (16u << 20));           // 32*4098*512 B = 67.1 MB
    const size_t need = (16u << 20) + (size_t)B_ * LP_ * 512;

    if (ws_size >= need) {
        poolcvt_k<<<1024, 256, 0, stream>>>(x, xbf, part);
        att_k<<<32, 256, 0, stream>>>(part, w_fc, bn_g, bn_b, bn_m, bn_v,
                                      w_ch, b_ch, w_fil, b_fil, w_sp, b_sp, w_ker, b_ker,
                                      ch_att, fil_att, sp_att, ker_att);
        wfrag_k<<<512, 256, 0, stream>>>(weight, ch_att, fil_att, sp_att, ker_att, wfrag);
        conv_k<<<2048, 256, 0, stream>>>(xbf, wfrag, out);
    } else {
        pool_partial_k<<<1024, 256, 0, stream>>>(x, part);
        att_k<<<32, 256, 0, stream>>>(part, w_fc, bn_g, bn_b, bn_m, bn_v,
                                      w_ch, b_ch, w_fil, b_fil, w_sp, b_sp, w_ker, b_ker,
                                      ch_att, fil_att, sp_att, ker_att);
        wfrag_k<<<512, 256, 0, stream>>>(weight, ch_att, fil_att, sp_att, ker_att, wfrag);
        conv_fb_k<<<1024, 512, 0, stream>>>(x, wfrag, out);
    }
}